// Round 9
// baseline (297.208 us; speedup 1.0000x reference)
//
#include <hip/hip_runtime.h>
#include <math.h>

// Problem constants
#define B_   16
#define T_   64
#define N_   22
#define D_   64
#define K_   4
#define E_   8
#define H_   64
#define TW   59                 // valid time steps per batch (t=2..60 absolute)
#define M_   (B_ * TW)          // 944
#define NE_  (N_ * E_)          // 176
#define NDXT (N_ * D_)          // 1408

typedef __attribute__((ext_vector_type(8))) short short8;
typedef __attribute__((ext_vector_type(4))) float float4v;

union Frag {
    short8 s8;
    unsigned u[4];
};

#define HIMG_ROW 68        // dwords per h-image row (64 + 4 pad)

// trunc-split: hi = trunc bf16, lo = trunc bf16 of residual.
__device__ inline void split2(float f, unsigned& hi, unsigned& lo) {
    unsigned u  = __float_as_uint(f);
    unsigned ht = u & 0xffff0000u;
    float rem   = f - __uint_as_float(ht);
    hi = u >> 16;
    lo = __float_as_uint(rem) >> 16;
}

// ---------------------------------------------------------------------------
// Main kernel. Block = (n, e, mtile of 128 rows); swizzle g = mt + 8*e + 64*n
// -> XCD = mt (x fp32 slab ~1.6 MB/XCD stays L2-resident; W streams via L3).
// K-loop: ONE barrier per chunk. LDS W double-buffer: read wbuf[c&1] while
// storing chunk c+1 into wbuf[(c+1)&1]. Register pipelines (all 1 chunk deep,
// completion guaranteed by the barrier's vmcnt(0) drain):
//   W: load fp32 c+2 -> wf[c&1]; pack c+1 from wf[(c+1)&1]; store c+1.
//   A: fp32 loads for c+1 issued at top of c; split at top of c+1.
// (256,2): ~190 VGPR live set, no spill; 2 blocks/CU at 67.6 KB LDS.
__global__ __launch_bounds__(256, 2) void moe_err_kernel(
    const float* __restrict__ x, const int* __restrict__ nb,
    const float* __restrict__ W1, const float* __restrict__ W2,
    const float* __restrict__ W3,
    const float* __restrict__ b1, const float* __restrict__ b2,
    const float* __restrict__ b3, float* __restrict__ err_ws)
{
    const int tid = threadIdx.x;
    const int w   = tid >> 6;
    const int L   = tid & 63;
    const int g   = blockIdx.x;
    const int mt  = g & 7;            // XCD = mt
    const int e   = (g >> 3) & 7;
    const int n   = g >> 6;
    const int ne  = n * E_ + e;

    __shared__ __align__(16) char smem[67584];
    char* wbuf0 = smem;                            // 16 KB: chunk images (even)
    char* wbuf1 = smem + 16384;                    // 16 KB: chunk images (odd)
    unsigned* himg = (unsigned*)(smem + 32768);    // 34,816 B: 128 x 68 dwords

    const int lrow = L & 15;           // A row within 16
    const int dseg = (L >> 4) * 8;     // k-subsegment (elements)
    const int ccol = L & 15;           // C col within 16-group
    const int qrow = (L >> 4) * 4;     // C row quad base
    const int rowbase = mt * 128 + w * 32;

    // per-rowtile lane row -> base into x (fp32)
    const float* xrow[2];
    #pragma unroll
    for (int rt = 0; rt < 2; ++rt) {
        int m  = rowbase + rt * 16 + lrow;
        int mc = m < M_ ? m : M_ - 1;
        int b = mc / TW, t = mc % TW;
        xrow[rt] = x + (size_t)(b * T_ + t) * NDXT;
    }

    // neighbor offsets (wave-uniform scalars)
    const int o0 = __builtin_amdgcn_readfirstlane(nb[n * K_ + 0]) * D_;
    const int o1 = __builtin_amdgcn_readfirstlane(nb[n * K_ + 1]) * D_;
    const int o2 = __builtin_amdgcn_readfirstlane(nb[n * K_ + 2]) * D_;
    const int o3 = __builtin_amdgcn_readfirstlane(nb[n * K_ + 3]) * D_;

    const float* W1ne = W1 + (size_t)ne * (1280 * 64);
    const float* W2ne = W2 + (size_t)ne * 4096;
    const float* W3ne = W3 + (size_t)ne * 4096;
    auto csrc = [&](int c) {
        return c < 20 ? (W1ne + (size_t)c * 4096) : (c == 20 ? W2ne : W3ne);
    };

    // ---- W register pipeline (wave w owns image pairs 2w, 2w+1) ----
    float wf[2][2][8];                 // [buf][pair][j]
    uint4 wph[2], wpl[2];
    auto loadWf = [&](int wb, const float* src) {
        #pragma unroll
        for (int p = 0; p < 2; ++p) {
            const int pi = 2 * w + p;
            const float* sp = src + ((pi >> 2) * 32 + (L >> 4) * 8) * 64
                                  + ((pi & 3) * 16 + (L & 15));
            #pragma unroll
            for (int j = 0; j < 8; ++j) wf[wb][p][j] = sp[j * 64];
        }
    };
    auto packW = [&](int wb) {
        #pragma unroll
        for (int p = 0; p < 2; ++p) {
            unsigned hs[8], ls[8];
            #pragma unroll
            for (int j = 0; j < 8; ++j) split2(wf[wb][p][j], hs[j], ls[j]);
            wph[p].x = hs[0] | (hs[1] << 16); wph[p].y = hs[2] | (hs[3] << 16);
            wph[p].z = hs[4] | (hs[5] << 16); wph[p].w = hs[6] | (hs[7] << 16);
            wpl[p].x = ls[0] | (ls[1] << 16); wpl[p].y = ls[2] | (ls[3] << 16);
            wpl[p].z = ls[4] | (ls[5] << 16); wpl[p].w = ls[6] | (ls[7] << 16);
        }
    };
    auto storeW = [&](char* buf) {
        #pragma unroll
        for (int p = 0; p < 2; ++p) {
            char* bp = buf + (size_t)(2 * w + p) * 2048 + (size_t)L * 16;
            *(uint4*)bp          = wph[p];
            *(uint4*)(bp + 1024) = wpl[p];
        }
    };
    auto bfrag = [&](const char* buf, int s2, int cf, int hl) -> short8 {
        return *(const short8*)(buf + (size_t)((s2 * 4 + cf) * 2 + hl) * 1024
                                    + (size_t)L * 16);
    };

    // ---- A register pipeline: fp32 in-flight buffer + split frags ----
    float4 af[2][2][2];                // [s2][rt][half] fp32 chunk in flight
    Frag ah[2][2], al[2][2];           // [s2][rt] current-chunk bf16 hi/lo
    auto loadA = [&](int off) {
        #pragma unroll
        for (int s2 = 0; s2 < 2; ++s2)
            #pragma unroll
            for (int rt = 0; rt < 2; ++rt) {
                const float* p = xrow[rt] + off + s2 * 32 + dseg;
                af[s2][rt][0] = *(const float4*)p;
                af[s2][rt][1] = *(const float4*)(p + 4);
            }
    };
    auto splitA = [&]() {
        #pragma unroll
        for (int s2 = 0; s2 < 2; ++s2)
            #pragma unroll
            for (int rt = 0; rt < 2; ++rt) {
                float f[8] = {af[s2][rt][0].x, af[s2][rt][0].y, af[s2][rt][0].z, af[s2][rt][0].w,
                              af[s2][rt][1].x, af[s2][rt][1].y, af[s2][rt][1].z, af[s2][rt][1].w};
                unsigned hs[8], ls[8];
                #pragma unroll
                for (int j = 0; j < 8; ++j) split2(f[j], hs[j], ls[j]);
                #pragma unroll
                for (int i = 0; i < 4; ++i) {
                    ah[s2][rt].u[i] = hs[2 * i] | (hs[2 * i + 1] << 16);
                    al[s2][rt].u[i] = ls[2 * i] | (ls[2 * i + 1] << 16);
                }
            }
    };

    // ---- prologue ----
    loadWf(0, csrc(0));                // chunk 0 -> wf[0]
    loadWf(1, csrc(1));                // chunk 1 -> wf[1]
    loadA(0 * NDXT + o0);              // chunk 0 fp32 A
    packW(0);                          // (waits wf[0] loads)
    storeW(wbuf0);                     // chunk 0 images
    __syncthreads();                   // B0: wbuf0 visible; drains all vmem

    float4v acc1[2][4];
    #pragma unroll
    for (int rt = 0; rt < 2; ++rt)
        #pragma unroll
        for (int cf = 0; cf < 4; ++cf) acc1[rt][cf] = (float4v)0.f;

    // ---------------- GEMM1: 20 chunks of K=64, 1 barrier each --------------
    for (int dt = 0; dt < 5; ++dt) {
        #pragma unroll
        for (int kk = 0; kk < 4; ++kk) {
            const int c = dt * 4 + kk;
            // A: split chunk c (loads drained by last barrier); issue c+1
            splitA();
            if (c < 19) {
                const int dtn = (kk == 3) ? dt + 1 : dt;
                const int okn = (kk == 0) ? o1 : ((kk == 1) ? o2 : ((kk == 2) ? o3 : o0));
                loadA(dtn * NDXT + okn);
            }
            // W: pack c+1 (loaded during c-1, drained); store -> other buffer;
            //    issue load of c+2 into the wf buffer freed by the pack.
            packW((c + 1) & 1);
            storeW((c & 1) ? wbuf0 : wbuf1);
            loadWf(c & 1, csrc(c + 2));

            // compute chunk c from wbuf[c&1]
            const char* wb = (c & 1) ? wbuf1 : wbuf0;
            #pragma unroll
            for (int s2 = 0; s2 < 2; ++s2)
                #pragma unroll
                for (int cf = 0; cf < 4; ++cf) {
                    short8 bh = bfrag(wb, s2, cf, 0);
                    short8 bl = bfrag(wb, s2, cf, 1);
                    #pragma unroll
                    for (int rt = 0; rt < 2; ++rt) {
                        acc1[rt][cf] = __builtin_amdgcn_mfma_f32_16x16x32_bf16(ah[s2][rt].s8, bh, acc1[rt][cf], 0, 0, 0);
                        acc1[rt][cf] = __builtin_amdgcn_mfma_f32_16x16x32_bf16(ah[s2][rt].s8, bl, acc1[rt][cf], 0, 0, 0);
                        acc1[rt][cf] = __builtin_amdgcn_mfma_f32_16x16x32_bf16(al[s2][rt].s8, bh, acc1[rt][cf], 0, 0, 0);
                    }
                }
            __syncthreads();          // B_{c+1}: c+1 images visible; drains vmem
        }
    }
    // post-loop state: wbuf0 = W2 images (stored during c=19); wf[1] = W3 fp32.

    // ---------------- h1 -> himg; stage W3 -> wbuf1; GEMM2 ------------------
    packW(1);                          // W3 (drained at B20)
    storeW(wbuf1);
    #pragma unroll
    for (int cf = 0; cf < 4; ++cf) {
        float bv = b1[(size_t)ne * H_ + cf * 16 + ccol];
        #pragma unroll
        for (int rt = 0; rt < 2; ++rt)
            #pragma unroll
            for (int reg = 0; reg < 4; ++reg) {
                float hv = fmaxf(acc1[rt][cf][reg] + bv, 0.f);
                unsigned hi, lo;
                split2(hv, hi, lo);
                himg[(w * 32 + rt * 16 + qrow + reg) * HIMG_ROW + cf * 16 + ccol] =
                    (hi << 16) | lo;               // wave-private rows
            }
    }

    float4v acc2[2][4];
    #pragma unroll
    for (int rt = 0; rt < 2; ++rt)
        #pragma unroll
        for (int cf = 0; cf < 4; ++cf) acc2[rt][cf] = (float4v)0.f;
    #pragma unroll
    for (int s2 = 0; s2 < 2; ++s2) {
        Frag ha[2], la[2];
        #pragma unroll
        for (int rt = 0; rt < 2; ++rt) {
            const unsigned* hp = himg + (w * 32 + rt * 16 + lrow) * HIMG_ROW + s2 * 32 + dseg;
            uint4 u0 = *(const uint4*)hp;
            uint4 u1 = *(const uint4*)(hp + 4);
            unsigned uu[8] = {u0.x, u0.y, u0.z, u0.w, u1.x, u1.y, u1.z, u1.w};
            #pragma unroll
            for (int i = 0; i < 4; ++i) {
                ha[rt].u[i] = (uu[2 * i] >> 16) | (uu[2 * i + 1] & 0xffff0000u);
                la[rt].u[i] = (uu[2 * i] & 0xffffu) | (uu[2 * i + 1] << 16);
            }
        }
        #pragma unroll
        for (int cf = 0; cf < 4; ++cf) {
            short8 bh = bfrag(wbuf0, s2, cf, 0);
            short8 bl = bfrag(wbuf0, s2, cf, 1);
            #pragma unroll
            for (int rt = 0; rt < 2; ++rt) {
                acc2[rt][cf] = __builtin_amdgcn_mfma_f32_16x16x32_bf16(ha[rt].s8, bh, acc2[rt][cf], 0, 0, 0);
                acc2[rt][cf] = __builtin_amdgcn_mfma_f32_16x16x32_bf16(ha[rt].s8, bl, acc2[rt][cf], 0, 0, 0);
                acc2[rt][cf] = __builtin_amdgcn_mfma_f32_16x16x32_bf16(la[rt].s8, bh, acc2[rt][cf], 0, 0, 0);
            }
        }
    }
    __syncthreads();                   // W3 images visible

    // ---------------- h2 -> himg (own rows); GEMM3; err epilogue ------------
    #pragma unroll
    for (int cf = 0; cf < 4; ++cf) {
        float bv = b2[(size_t)ne * H_ + cf * 16 + ccol];
        #pragma unroll
        for (int rt = 0; rt < 2; ++rt)
            #pragma unroll
            for (int reg = 0; reg < 4; ++reg) {
                float hv = fmaxf(acc2[rt][cf][reg] + bv, 0.f);
                unsigned hi, lo;
                split2(hv, hi, lo);
                himg[(w * 32 + rt * 16 + qrow + reg) * HIMG_ROW + cf * 16 + ccol] =
                    (hi << 16) | lo;
            }
    }

    float4v acc3[2][4];
    #pragma unroll
    for (int rt = 0; rt < 2; ++rt)
        #pragma unroll
        for (int cf = 0; cf < 4; ++cf) acc3[rt][cf] = (float4v)0.f;
    #pragma unroll
    for (int s2 = 0; s2 < 2; ++s2) {
        Frag ha[2], la[2];
        #pragma unroll
        for (int rt = 0; rt < 2; ++rt) {
            const unsigned* hp = himg + (w * 32 + rt * 16 + lrow) * HIMG_ROW + s2 * 32 + dseg;
            uint4 u0 = *(const uint4*)hp;
            uint4 u1 = *(const uint4*)(hp + 4);
            unsigned uu[8] = {u0.x, u0.y, u0.z, u0.w, u1.x, u1.y, u1.z, u1.w};
            #pragma unroll
            for (int i = 0; i < 4; ++i) {
                ha[rt].u[i] = (uu[2 * i] >> 16) | (uu[2 * i + 1] & 0xffff0000u);
                la[rt].u[i] = (uu[2 * i] & 0xffffu) | (uu[2 * i + 1] << 16);
            }
        }
        #pragma unroll
        for (int cf = 0; cf < 4; ++cf) {
            short8 bh = bfrag(wbuf1, s2, cf, 0);
            short8 bl = bfrag(wbuf1, s2, cf, 1);
            #pragma unroll
            for (int rt = 0; rt < 2; ++rt) {
                acc3[rt][cf] = __builtin_amdgcn_mfma_f32_16x16x32_bf16(ha[rt].s8, bh, acc3[rt][cf], 0, 0, 0);
                acc3[rt][cf] = __builtin_amdgcn_mfma_f32_16x16x32_bf16(ha[rt].s8, bl, acc3[rt][cf], 0, 0, 0);
                acc3[rt][cf] = __builtin_amdgcn_mfma_f32_16x16x32_bf16(la[rt].s8, bh, acc3[rt][cf], 0, 0, 0);
            }
        }
    }

    {
        float b3v[4];
        #pragma unroll
        for (int cf = 0; cf < 4; ++cf) b3v[cf] = b3[(size_t)ne * D_ + cf * 16 + ccol];

        #pragma unroll
        for (int rt = 0; rt < 2; ++rt) {
            #pragma unroll
            for (int reg = 0; reg < 4; ++reg) {
                const int m  = rowbase + rt * 16 + qrow + reg;
                const int mc = m < M_ ? m : M_ - 1;
                const int b = mc / TW, t = mc % TW;
                const float* yp = x + ((size_t)(b * T_ + t + 2) * N_ + n) * D_;
                float s = 0.f;
                #pragma unroll
                for (int cf = 0; cf < 4; ++cf) {
                    float d = acc3[rt][cf][reg] + b3v[cf] - yp[cf * 16 + ccol];
                    s += d * d;
                }
                s += __shfl_xor(s, 1);
                s += __shfl_xor(s, 2);
                s += __shfl_xor(s, 4);
                s += __shfl_xor(s, 8);
                if (ccol == 0 && m < M_) {
                    err_ws[((size_t)m * N_ + n) * E_ + e] = s * (1.f / 64.f);
                }
            }
        }
    }
}

// ---------------------------------------------------------------------------
// Fused reduce: single block, 1024 threads. No atomics, no init kernel.
__global__ __launch_bounds__(1024) void moe_reduce_kernel(
    const float* __restrict__ err_ws, float* __restrict__ out)
{
    const int tid = threadIdx.x;
    float partial = 0.f;
    for (int idx = tid; idx < M_ * N_; idx += 1024) {
        const int m = idx / N_, n = idx % N_;
        const float* ep = err_ws + (size_t)idx * E_;
        float ev[E_];
        float4 e0 = *(const float4*)ep;
        float4 e1 = *(const float4*)(ep + 4);
        ev[0] = e0.x; ev[1] = e0.y; ev[2] = e0.z; ev[3] = e0.w;
        ev[4] = e1.x; ev[5] = e1.y; ev[6] = e1.z; ev[7] = e1.w;
        float mn = ev[0];
        int am = 0;
        #pragma unroll
        for (int i = 1; i < E_; ++i) {
            if (ev[i] < mn) { mn = ev[i]; am = i; }
        }
        float p[E_];
        float Z = 0.f;
        #pragma unroll
        for (int i = 0; i < E_; ++i) { p[i] = expf(mn - ev[i]); Z += p[i]; }
        const float invZ = 1.f / Z;
        float kl = 0.f;
        #pragma unroll
        for (int i = 0; i < E_; ++i) {
            float q = p[i] * invZ;
            kl += q * (logf(q + 1e-9f) + 2.0794415416798357f);  // log(8)
        }
        partial += mn + 0.01f * kl;
        const int t = m % TW, b = m / TW;
        if (t == TW - 1 && n == N_ - 1) out[1 + b] = (float)am;
    }
    __shared__ float sd[1024];
    sd[tid] = partial;
    __syncthreads();
    for (int s = 512; s > 0; s >>= 1) {
        if (tid < s) sd[tid] += sd[tid + s];
        __syncthreads();
    }
    if (tid == 0) out[0] = sd[0] * (1.f / 20160.f);  // / B / (N-1) / (T-4)
}

extern "C" void kernel_launch(void* const* d_in, const int* in_sizes, int n_in,
                              void* d_out, int out_size, void* d_ws, size_t ws_size,
                              hipStream_t stream)
{
    const float* x  = (const float*)d_in[0];
    const int*   nb = (const int*)d_in[1];
    const float* W1 = (const float*)d_in[2];
    const float* b1 = (const float*)d_in[3];
    const float* W2 = (const float*)d_in[4];
    const float* b2 = (const float*)d_in[5];
    const float* W3 = (const float*)d_in[6];
    const float* b3 = (const float*)d_in[7];
    float* out    = (float*)d_out;
    float* err_ws = (float*)d_ws;    // 664,576 B — only ws use

    hipLaunchKernelGGL(moe_err_kernel, dim3(NE_ * 8), dim3(256), 0, stream,
                       x, nb, W1, W2, W3, b1, b2, b3, err_ws);
    hipLaunchKernelGGL(moe_reduce_kernel, dim3(1), dim3(1024), 0, stream, err_ws, out);
}

// Round 10
// 268.959 us; speedup vs baseline: 1.1050x; 1.1050x over previous
//
#include <hip/hip_runtime.h>
#include <math.h>

// Problem constants
#define B_   16
#define T_   64
#define N_   22
#define D_   64
#define K_   4
#define E_   8
#define H_   64
#define TW   59                 // valid time steps per batch (t=2..60 absolute)
#define M_   (B_ * TW)          // 944
#define NE_  (N_ * E_)          // 176
#define NDXT (N_ * D_)          // 1408
#define XTOT (B_ * T_ * N_ * D_)   // 1,441,792

typedef __attribute__((ext_vector_type(8))) short short8;
typedef __attribute__((ext_vector_type(4))) float float4v;

// workspace layout
#define ERRWS_BYTES  ((size_t)(M_ * N_ * E_) * 4)          // 664,576
#define XH_OFF       (ERRWS_BYTES)

// round-to-nearest-even-ish bf16 (RTN with tie-to-even bit): unbiased.
__device__ inline unsigned rtn_bf16(float f) {
    unsigned u = __float_as_uint(f);
    return (u + 0x7fffu + ((u >> 16) & 1u)) >> 16;
}

// ---------------------------------------------------------------------------
// Precompute: x -> bf16 (RTN) image, same linear layout. ~9 MB traffic.
__global__ __launch_bounds__(256) void xtrunc_kernel(
    const float* __restrict__ x, short* __restrict__ xh)
{
    int i = (blockIdx.x * 256 + threadIdx.x) * 4;
    if (i >= XTOT) return;
    float4 v = *(const float4*)(x + i);
    uint2 hp;
    hp.x = rtn_bf16(v.x) | (rtn_bf16(v.y) << 16);
    hp.y = rtn_bf16(v.z) | (rtn_bf16(v.w) << 16);
    *(uint2*)(xh + i) = hp;
}

// ---------------------------------------------------------------------------
// Main kernel, plain-bf16 (1-product). Block = (n, e, mtile of 128 rows);
// swizzle g = e + 8*mt + 64*n -> XCD = e: the 8 mt-blocks of one (n,e) are
// consecutive on one XCD, so W1ne (336 KB) is read ~once per XCD (R7 lesson);
// A (xh, 2.9 MB bf16 total) is small enough to sit in L2/L3.
// W: fp32 stream -> in-register RTN-pack -> 8 KB LDS image buffer, 1 chunk
// ahead (R8 2-barrier structure, proven best). A: direct 16B global loads.
// h1/h2: bf16 shorts in LDS, written in C-layout, read directly as A-frags.
// (256,4): ~110 VGPR live set -> 4 blocks/CU, 26.6 KB LDS.
__global__ __launch_bounds__(256, 4) void moe_err_kernel(
    const float* __restrict__ x, const short* __restrict__ xh,
    const int* __restrict__ nb,
    const float* __restrict__ W1, const float* __restrict__ W2,
    const float* __restrict__ W3,
    const float* __restrict__ b1, const float* __restrict__ b2,
    const float* __restrict__ b3, float* __restrict__ err_ws)
{
    const int tid = threadIdx.x;
    const int w   = tid >> 6;
    const int L   = tid & 63;
    const int g   = blockIdx.x;
    const int e   = g & 7;            // XCD = e
    const int mt  = (g >> 3) & 7;
    const int n   = g >> 6;
    const int ne  = n * E_ + e;

    __shared__ __align__(16) char smem[26624];
    char*  wbuf   = smem;                       // 8 KB: 8 W images x 1 KB (hi)
    short* himg   = (short*)(smem + 8192);      // 18,432 B: 128 rows x 72 shorts

    const int lrow = L & 15;           // A row within 16
    const int dseg = (L >> 4) * 8;     // k-subsegment (elements)
    const int ccol = L & 15;           // C col within 16-group
    const int qrow = (L >> 4) * 4;     // C row quad base
    const int rowbase = mt * 128 + w * 32;

    // per-rowtile lane row -> base into xh
    const short* xhrow[2];
    #pragma unroll
    for (int rt = 0; rt < 2; ++rt) {
        int m  = rowbase + rt * 16 + lrow;
        int mc = m < M_ ? m : M_ - 1;
        int b = mc / TW, t = mc % TW;
        xhrow[rt] = xh + (size_t)(b * T_ + t) * NDXT;
    }

    // neighbor offsets (wave-uniform scalars)
    const int o0 = __builtin_amdgcn_readfirstlane(nb[n * K_ + 0]) * D_;
    const int o1 = __builtin_amdgcn_readfirstlane(nb[n * K_ + 1]) * D_;
    const int o2 = __builtin_amdgcn_readfirstlane(nb[n * K_ + 2]) * D_;
    const int o3 = __builtin_amdgcn_readfirstlane(nb[n * K_ + 3]) * D_;

    const float* W1ne = W1 + (size_t)ne * (1280 * 64);
    const float* W2ne = W2 + (size_t)ne * 4096;
    const float* W3ne = W3 + (size_t)ne * 4096;
    auto csrc = [&](int c) {
        return c < 20 ? (W1ne + (size_t)c * 4096) : (c == 20 ? W2ne : W3ne);
    };

    // ---- W pipeline: wave w owns images 2w, 2w+1 (image = s2*4+cf) ----
    float wf[2][8];                    // fp32 in flight (single-deep)
    uint4 wph[2];                      // packed bf16 hi
    auto loadWf = [&](const float* src) {
        #pragma unroll
        for (int p = 0; p < 2; ++p) {
            const int pi = 2 * w + p;
            const float* sp = src + ((pi >> 2) * 32 + (L >> 4) * 8) * 64
                                  + ((pi & 3) * 16 + (L & 15));
            #pragma unroll
            for (int j = 0; j < 8; ++j) wf[p][j] = sp[j * 64];
        }
    };
    auto packW = [&]() {
        #pragma unroll
        for (int p = 0; p < 2; ++p) {
            unsigned hs[8];
            #pragma unroll
            for (int j = 0; j < 8; ++j) hs[j] = rtn_bf16(wf[p][j]);
            wph[p].x = hs[0] | (hs[1] << 16); wph[p].y = hs[2] | (hs[3] << 16);
            wph[p].z = hs[4] | (hs[5] << 16); wph[p].w = hs[6] | (hs[7] << 16);
        }
    };
    auto storeW = [&]() {
        #pragma unroll
        for (int p = 0; p < 2; ++p) {
            *(uint4*)(wbuf + (size_t)(2 * w + p) * 1024 + (size_t)L * 16) = wph[p];
        }
    };
    auto bfrag = [&](int s2, int cf) -> short8 {
        return *(const short8*)(wbuf + (size_t)(s2 * 4 + cf) * 1024
                                     + (size_t)L * 16);
    };

    loadWf(W1ne);
    packW();

    float4v acc1[2][4];
    #pragma unroll
    for (int rt = 0; rt < 2; ++rt)
        #pragma unroll
        for (int cf = 0; cf < 4; ++cf) acc1[rt][cf] = (float4v)0.f;

    // ---------------- GEMM1: 20 chunks of K=64 ----------------
    for (int dt = 0; dt < 5; ++dt) {
        #pragma unroll
        for (int kk = 0; kk < 4; ++kk) {
            const int c = dt * 4 + kk;
            __syncthreads();          // prev chunk's B-reads done
            storeW();                 // chunk c images
            __syncthreads();          // images visible

            loadWf(csrc(c + 1));      // issue next W fp32 loads (c=19 -> W2)

            const int okk = (kk == 0) ? o0 : ((kk == 1) ? o1 : ((kk == 2) ? o2 : o3));
            const int off = dt * NDXT + okk;

            short8 ah[2][2];          // [s2][rt]
            #pragma unroll
            for (int s2 = 0; s2 < 2; ++s2)
                #pragma unroll
                for (int rt = 0; rt < 2; ++rt)
                    ah[s2][rt] = *(const short8*)(xhrow[rt] + off + s2 * 32 + dseg);

            #pragma unroll
            for (int s2 = 0; s2 < 2; ++s2)
                #pragma unroll
                for (int cf = 0; cf < 4; ++cf) {
                    short8 bh = bfrag(s2, cf);
                    #pragma unroll
                    for (int rt = 0; rt < 2; ++rt)
                        acc1[rt][cf] = __builtin_amdgcn_mfma_f32_16x16x32_bf16(ah[s2][rt], bh, acc1[rt][cf], 0, 0, 0);
                }
            packW();                  // pack chunk c+1 (waits its loads)
        }
    }

    // ---------------- h1 -> bf16 himg; stage W2; GEMM2 ----------------------
    __syncthreads();                  // c19 B-reads done
    storeW();                         // W2 images
    #pragma unroll
    for (int cf = 0; cf < 4; ++cf) {
        float bv = b1[(size_t)ne * H_ + cf * 16 + ccol];
        #pragma unroll
        for (int rt = 0; rt < 2; ++rt)
            #pragma unroll
            for (int reg = 0; reg < 4; ++reg) {
                float hv = fmaxf(acc1[rt][cf][reg] + bv, 0.f);
                himg[(w * 32 + rt * 16 + qrow + reg) * 72 + cf * 16 + ccol] =
                    (short)rtn_bf16(hv);          // wave-private rows
            }
    }
    loadWf(W3ne);                     // issue W3 fp32 loads
    __syncthreads();                  // W2 images + h1 visible

    float4v acc2[2][4];
    #pragma unroll
    for (int rt = 0; rt < 2; ++rt)
        #pragma unroll
        for (int cf = 0; cf < 4; ++cf) acc2[rt][cf] = (float4v)0.f;
    #pragma unroll
    for (int s2 = 0; s2 < 2; ++s2) {
        short8 ha[2];
        #pragma unroll
        for (int rt = 0; rt < 2; ++rt)
            ha[rt] = *(const short8*)&himg[(w * 32 + rt * 16 + lrow) * 72 + s2 * 32 + dseg];
        #pragma unroll
        for (int cf = 0; cf < 4; ++cf) {
            short8 bh = bfrag(s2, cf);
            #pragma unroll
            for (int rt = 0; rt < 2; ++rt)
                acc2[rt][cf] = __builtin_amdgcn_mfma_f32_16x16x32_bf16(ha[rt], bh, acc2[rt][cf], 0, 0, 0);
        }
    }
    packW();                          // pack W3

    // ---------------- h2 -> bf16 himg; stage W3; GEMM3 ----------------------
    __syncthreads();                  // GEMM2's wbuf reads done
    storeW();                         // W3 images
    #pragma unroll
    for (int cf = 0; cf < 4; ++cf) {
        float bv = b2[(size_t)ne * H_ + cf * 16 + ccol];
        #pragma unroll
        for (int rt = 0; rt < 2; ++rt)
            #pragma unroll
            for (int reg = 0; reg < 4; ++reg) {
                float hv = fmaxf(acc2[rt][cf][reg] + bv, 0.f);
                himg[(w * 32 + rt * 16 + qrow + reg) * 72 + cf * 16 + ccol] =
                    (short)rtn_bf16(hv);
            }
    }
    __syncthreads();                  // W3 images + h2 visible

    float4v acc3[2][4];
    #pragma unroll
    for (int rt = 0; rt < 2; ++rt)
        #pragma unroll
        for (int cf = 0; cf < 4; ++cf) acc3[rt][cf] = (float4v)0.f;
    #pragma unroll
    for (int s2 = 0; s2 < 2; ++s2) {
        short8 ha[2];
        #pragma unroll
        for (int rt = 0; rt < 2; ++rt)
            ha[rt] = *(const short8*)&himg[(w * 32 + rt * 16 + lrow) * 72 + s2 * 32 + dseg];
        #pragma unroll
        for (int cf = 0; cf < 4; ++cf) {
            short8 bh = bfrag(s2, cf);
            #pragma unroll
            for (int rt = 0; rt < 2; ++rt)
                acc3[rt][cf] = __builtin_amdgcn_mfma_f32_16x16x32_bf16(ha[rt], bh, acc3[rt][cf], 0, 0, 0);
        }
    }

    // ---------------- err epilogue ----------------
    {
        float b3v[4];
        #pragma unroll
        for (int cf = 0; cf < 4; ++cf) b3v[cf] = b3[(size_t)ne * D_ + cf * 16 + ccol];

        #pragma unroll
        for (int rt = 0; rt < 2; ++rt) {
            #pragma unroll
            for (int reg = 0; reg < 4; ++reg) {
                const int m  = rowbase + rt * 16 + qrow + reg;
                const int mc = m < M_ ? m : M_ - 1;
                const int b = mc / TW, t = mc % TW;
                const float* yp = x + ((size_t)(b * T_ + t + 2) * N_ + n) * D_;
                float s = 0.f;
                #pragma unroll
                for (int cf = 0; cf < 4; ++cf) {
                    float d = acc3[rt][cf][reg] + b3v[cf] - yp[cf * 16 + ccol];
                    s += d * d;
                }
                s += __shfl_xor(s, 1);
                s += __shfl_xor(s, 2);
                s += __shfl_xor(s, 4);
                s += __shfl_xor(s, 8);
                if (ccol == 0 && m < M_) {
                    err_ws[((size_t)m * N_ + n) * E_ + e] = s * (1.f / 64.f);
                }
            }
        }
    }
}

// ---------------------------------------------------------------------------
// Exact fp32 fix-up for the 128 err cells that feed expert_idx
// (all b, t=TW-1, n=N-1, all e). Overwrites err_ws before the reduce.
__global__ __launch_bounds__(64) void fix_kernel(
    const float* __restrict__ x, const int* __restrict__ nb,
    const float* __restrict__ W1, const float* __restrict__ b1,
    const float* __restrict__ W2, const float* __restrict__ b2,
    const float* __restrict__ W3, const float* __restrict__ b3,
    float* __restrict__ err_ws)
{
    const int b = blockIdx.x >> 3;
    const int e = blockIdx.x & 7;
    const int n = N_ - 1;             // 21
    const int t = TW - 1;             // 58
    const int ne = n * E_ + e;
    const int j = threadIdx.x;        // 0..63

    __shared__ float fbuf[1280];
    __shared__ float h1s[64];
    __shared__ float h2s[64];

    // gather f: f[(dt*4+k)*64+d] = x[b, t+dt, nb[n,k], d]
    for (int i = j; i < 1280; i += 64) {
        int dt = i >> 8, r = i & 255;
        int k = r >> 6, d = r & 63;
        int nk = nb[n * K_ + k];
        fbuf[i] = x[(((size_t)(b * T_ + t + dt)) * N_ + nk) * D_ + d];
    }
    __syncthreads();

    const float* W1p = W1 + (size_t)ne * 1280 * 64;
    float s = b1[(size_t)ne * H_ + j];
    #pragma unroll 8
    for (int k = 0; k < 1280; ++k) s += fbuf[k] * W1p[(size_t)k * 64 + j];
    h1s[j] = fmaxf(s, 0.f);
    __syncthreads();

    const float* W2p = W2 + (size_t)ne * 4096;
    s = b2[(size_t)ne * H_ + j];
    #pragma unroll 8
    for (int k = 0; k < 64; ++k) s += h1s[k] * W2p[k * 64 + j];
    h2s[j] = fmaxf(s, 0.f);
    __syncthreads();

    const float* W3p = W3 + (size_t)ne * 4096;
    s = b3[(size_t)ne * D_ + j];
    #pragma unroll 8
    for (int k = 0; k < 64; ++k) s += h2s[k] * W3p[k * 64 + j];

    float y = x[(((size_t)(b * T_ + t + 2)) * N_ + n) * D_ + j];
    float d = s - y;
    float sq = d * d;
    sq += __shfl_xor(sq, 1);
    sq += __shfl_xor(sq, 2);
    sq += __shfl_xor(sq, 4);
    sq += __shfl_xor(sq, 8);
    sq += __shfl_xor(sq, 16);
    sq += __shfl_xor(sq, 32);
    if (j == 0) {
        int m = b * TW + t;
        err_ws[((size_t)m * N_ + n) * E_ + e] = sq * (1.f / 64.f);
    }
}

// ---------------------------------------------------------------------------
// Fused reduce: single block, 1024 threads. No atomics.
__global__ __launch_bounds__(1024) void moe_reduce_kernel(
    const float* __restrict__ err_ws, float* __restrict__ out)
{
    const int tid = threadIdx.x;
    float partial = 0.f;
    for (int idx = tid; idx < M_ * N_; idx += 1024) {
        const int m = idx / N_, n = idx % N_;
        const float* ep = err_ws + (size_t)idx * E_;
        float ev[E_];
        float4 e0 = *(const float4*)ep;
        float4 e1 = *(const float4*)(ep + 4);
        ev[0] = e0.x; ev[1] = e0.y; ev[2] = e0.z; ev[3] = e0.w;
        ev[4] = e1.x; ev[5] = e1.y; ev[6] = e1.z; ev[7] = e1.w;
        float mn = ev[0];
        int am = 0;
        #pragma unroll
        for (int i = 1; i < E_; ++i) {
            if (ev[i] < mn) { mn = ev[i]; am = i; }
        }
        float p[E_];
        float Z = 0.f;
        #pragma unroll
        for (int i = 0; i < E_; ++i) { p[i] = expf(mn - ev[i]); Z += p[i]; }
        const float invZ = 1.f / Z;
        float kl = 0.f;
        #pragma unroll
        for (int i = 0; i < E_; ++i) {
            float q = p[i] * invZ;
            kl += q * (logf(q + 1e-9f) + 2.0794415416798357f);  // log(8)
        }
        partial += mn + 0.01f * kl;
        const int t = m % TW, b = m / TW;
        if (t == TW - 1 && n == N_ - 1) out[1 + b] = (float)am;
    }
    __shared__ float sd[1024];
    sd[tid] = partial;
    __syncthreads();
    for (int s = 512; s > 0; s >>= 1) {
        if (tid < s) sd[tid] += sd[tid + s];
        __syncthreads();
    }
    if (tid == 0) out[0] = sd[0] * (1.f / 20160.f);  // / B / (N-1) / (T-4)
}

extern "C" void kernel_launch(void* const* d_in, const int* in_sizes, int n_in,
                              void* d_out, int out_size, void* d_ws, size_t ws_size,
                              hipStream_t stream)
{
    const float* x  = (const float*)d_in[0];
    const int*   nb = (const int*)d_in[1];
    const float* W1 = (const float*)d_in[2];
    const float* b1 = (const float*)d_in[3];
    const float* W2 = (const float*)d_in[4];
    const float* b2 = (const float*)d_in[5];
    const float* W3 = (const float*)d_in[6];
    const float* b3 = (const float*)d_in[7];
    float* out    = (float*)d_out;
    float* err_ws = (float*)d_ws;
    short* xh     = (short*)((char*)d_ws + XH_OFF);

    hipLaunchKernelGGL(xtrunc_kernel, dim3((XTOT / 4 + 255) / 256), dim3(256), 0, stream, x, xh);
    hipLaunchKernelGGL(moe_err_kernel, dim3(NE_ * 8), dim3(256), 0, stream,
                       x, xh, nb, W1, W2, W3, b1, b2, b3, err_ws);
    hipLaunchKernelGGL(fix_kernel, dim3(B_ * E_), dim3(64), 0, stream,
                       x, nb, W1, b1, W2, b2, W3, b3, err_ws);
    hipLaunchKernelGGL(moe_reduce_kernel, dim3(1), dim3(1024), 0, stream, err_ws, out);
}

// Round 11
// 204.724 us; speedup vs baseline: 1.4518x; 1.3138x over previous
//
#include <hip/hip_runtime.h>
#include <math.h>

// Problem constants
#define B_   16
#define T_   64
#define N_   22
#define D_   64
#define K_   4
#define E_   8
#define H_   64
#define TW   59                 // valid time steps per batch (t=2..60 absolute)
#define M_   (B_ * TW)          // 944
#define NE_  (N_ * E_)          // 176
#define NDXT (N_ * D_)          // 1408
#define XTOT (B_ * T_ * N_ * D_)   // 1,441,792

typedef __attribute__((ext_vector_type(8))) short short8;
typedef __attribute__((ext_vector_type(4))) float float4v;

// workspace layout
#define ERRWS_BYTES  ((size_t)(M_ * N_ * E_) * 4)          // 664,576
#define XH_OFF       (ERRWS_BYTES)

// round-to-nearest bf16 (with tie bit): unbiased.
__device__ inline unsigned rtn_bf16(float f) {
    unsigned u = __float_as_uint(f);
    return (u + 0x7fffu + ((u >> 16) & 1u)) >> 16;
}

// ---------------------------------------------------------------------------
// Precompute: x -> bf16 (RTN) image, same linear layout. Also zeroes out[0]
// (needed before reduce's atomicAdd; ordered by the stream).
__global__ __launch_bounds__(256) void xtrunc_kernel(
    const float* __restrict__ x, short* __restrict__ xh, float* __restrict__ out)
{
    if (blockIdx.x == 0 && threadIdx.x == 0) out[0] = 0.f;
    int i = (blockIdx.x * 256 + threadIdx.x) * 4;
    if (i >= XTOT) return;
    float4 v = *(const float4*)(x + i);
    uint2 hp;
    hp.x = rtn_bf16(v.x) | (rtn_bf16(v.y) << 16);
    hp.y = rtn_bf16(v.z) | (rtn_bf16(v.w) << 16);
    *(uint2*)(xh + i) = hp;
}

// ---------------------------------------------------------------------------
// Main kernel, plain-bf16. Block = (n, e, mtile of 128 rows);
// swizzle g = e + 8*mt + 64*n -> XCD = e (8 mt-blocks of one (n,e) co-XCD:
// W1ne read ~once). W: fp32 stream -> 2-DEEP register prefetch (wf dbuf:
// packW(c+1) consumes loads issued at c-1 -> full-chunk latency cover) ->
// RTN-pack -> 8 KB LDS image buffer. A: direct 16B global loads from xh.
// h1/h2: bf16 shorts in LDS (C-layout write = A-frag read). (256,4).
__global__ __launch_bounds__(256, 4) void moe_err_kernel(
    const float* __restrict__ x, const short* __restrict__ xh,
    const int* __restrict__ nb,
    const float* __restrict__ W1, const float* __restrict__ W2,
    const float* __restrict__ W3,
    const float* __restrict__ b1, const float* __restrict__ b2,
    const float* __restrict__ b3, float* __restrict__ err_ws)
{
    const int tid = threadIdx.x;
    const int w   = tid >> 6;
    const int L   = tid & 63;
    const int g   = blockIdx.x;
    const int e   = g & 7;            // XCD = e
    const int mt  = (g >> 3) & 7;
    const int n   = g >> 6;
    const int ne  = n * E_ + e;

    __shared__ __align__(16) char smem[26624];
    char*  wbuf   = smem;                       // 8 KB: 8 W images x 1 KB
    short* himg   = (short*)(smem + 8192);      // 18,432 B: 128 rows x 72 shorts

    const int lrow = L & 15;           // A row within 16
    const int dseg = (L >> 4) * 8;     // k-subsegment (elements)
    const int ccol = L & 15;           // C col within 16-group
    const int qrow = (L >> 4) * 4;     // C row quad base
    const int rowbase = mt * 128 + w * 32;

    // per-rowtile lane row -> base into xh
    const short* xhrow[2];
    #pragma unroll
    for (int rt = 0; rt < 2; ++rt) {
        int m  = rowbase + rt * 16 + lrow;
        int mc = m < M_ ? m : M_ - 1;
        int b = mc / TW, t = mc % TW;
        xhrow[rt] = xh + (size_t)(b * T_ + t) * NDXT;
    }

    // neighbor offsets (wave-uniform scalars)
    const int o0 = __builtin_amdgcn_readfirstlane(nb[n * K_ + 0]) * D_;
    const int o1 = __builtin_amdgcn_readfirstlane(nb[n * K_ + 1]) * D_;
    const int o2 = __builtin_amdgcn_readfirstlane(nb[n * K_ + 2]) * D_;
    const int o3 = __builtin_amdgcn_readfirstlane(nb[n * K_ + 3]) * D_;

    const float* W1ne = W1 + (size_t)ne * (1280 * 64);
    const float* W2ne = W2 + (size_t)ne * 4096;
    const float* W3ne = W3 + (size_t)ne * 4096;
    auto csrc = [&](int c) {
        return c < 20 ? (W1ne + (size_t)c * 4096) : (c == 20 ? W2ne : W3ne);
    };

    // ---- W pipeline: wave w owns images 2w, 2w+1 (image = s2*4+cf) ----
    float wf[2][2][8];                 // [buf][pair][j] fp32, 2 chunks deep
    uint4 wph[2];                      // packed bf16
    auto loadWf = [&](int wb, const float* src) {
        #pragma unroll
        for (int p = 0; p < 2; ++p) {
            const int pi = 2 * w + p;
            const float* sp = src + ((pi >> 2) * 32 + (L >> 4) * 8) * 64
                                  + ((pi & 3) * 16 + (L & 15));
            #pragma unroll
            for (int j = 0; j < 8; ++j) wf[wb][p][j] = sp[j * 64];
        }
    };
    auto packW = [&](int wb) {
        #pragma unroll
        for (int p = 0; p < 2; ++p) {
            unsigned hs[8];
            #pragma unroll
            for (int j = 0; j < 8; ++j) hs[j] = rtn_bf16(wf[wb][p][j]);
            wph[p].x = hs[0] | (hs[1] << 16); wph[p].y = hs[2] | (hs[3] << 16);
            wph[p].z = hs[4] | (hs[5] << 16); wph[p].w = hs[6] | (hs[7] << 16);
        }
    };
    auto storeW = [&]() {
        #pragma unroll
        for (int p = 0; p < 2; ++p) {
            *(uint4*)(wbuf + (size_t)(2 * w + p) * 1024 + (size_t)L * 16) = wph[p];
        }
    };
    auto bfrag = [&](int s2, int cf) -> short8 {
        return *(const short8*)(wbuf + (size_t)(s2 * 4 + cf) * 1024
                                     + (size_t)L * 16);
    };

    // prologue: chunk0 -> wf[0], chunk1 -> wf[1]; pack chunk0
    loadWf(0, csrc(0));
    loadWf(1, csrc(1));
    packW(0);

    float4v acc1[2][4];
    #pragma unroll
    for (int rt = 0; rt < 2; ++rt)
        #pragma unroll
        for (int cf = 0; cf < 4; ++cf) acc1[rt][cf] = (float4v)0.f;

    // ---------------- GEMM1: 20 chunks of K=64 ----------------
    for (int dt = 0; dt < 5; ++dt) {
        #pragma unroll
        for (int kk = 0; kk < 4; ++kk) {
            const int c = dt * 4 + kk;
            __syncthreads();          // prev chunk's B-reads done
            storeW();                 // chunk c images
            __syncthreads();          // images visible

            loadWf(c & 1, csrc(c + 2));   // c+2 <= 21; refills freed buffer

            const int okk = (kk == 0) ? o0 : ((kk == 1) ? o1 : ((kk == 2) ? o2 : o3));
            const int off = dt * NDXT + okk;

            short8 ah[2][2];          // [s2][rt]
            #pragma unroll
            for (int s2 = 0; s2 < 2; ++s2)
                #pragma unroll
                for (int rt = 0; rt < 2; ++rt)
                    ah[s2][rt] = *(const short8*)(xhrow[rt] + off + s2 * 32 + dseg);

            #pragma unroll
            for (int s2 = 0; s2 < 2; ++s2)
                #pragma unroll
                for (int cf = 0; cf < 4; ++cf) {
                    short8 bh = bfrag(s2, cf);
                    #pragma unroll
                    for (int rt = 0; rt < 2; ++rt)
                        acc1[rt][cf] = __builtin_amdgcn_mfma_f32_16x16x32_bf16(ah[s2][rt], bh, acc1[rt][cf], 0, 0, 0);
                }
            packW((c + 1) & 1);       // chunk c+1 (loaded at c-1: full cover)
        }
    }
    // post-loop: wph = W2 (packed at c=19); wf[1] holds W3 fp32 (loaded at c=19)

    // ---------------- h1 -> bf16 himg; stage W2; GEMM2 ----------------------
    __syncthreads();                  // c19 B-reads done
    storeW();                         // W2 images
    #pragma unroll
    for (int cf = 0; cf < 4; ++cf) {
        float bv = b1[(size_t)ne * H_ + cf * 16 + ccol];
        #pragma unroll
        for (int rt = 0; rt < 2; ++rt)
            #pragma unroll
            for (int reg = 0; reg < 4; ++reg) {
                float hv = fmaxf(acc1[rt][cf][reg] + bv, 0.f);
                himg[(w * 32 + rt * 16 + qrow + reg) * 72 + cf * 16 + ccol] =
                    (short)rtn_bf16(hv);          // wave-private rows
            }
    }
    __syncthreads();                  // W2 images + h1 visible

    float4v acc2[2][4];
    #pragma unroll
    for (int rt = 0; rt < 2; ++rt)
        #pragma unroll
        for (int cf = 0; cf < 4; ++cf) acc2[rt][cf] = (float4v)0.f;
    #pragma unroll
    for (int s2 = 0; s2 < 2; ++s2) {
        short8 ha[2];
        #pragma unroll
        for (int rt = 0; rt < 2; ++rt)
            ha[rt] = *(const short8*)&himg[(w * 32 + rt * 16 + lrow) * 72 + s2 * 32 + dseg];
        #pragma unroll
        for (int cf = 0; cf < 4; ++cf) {
            short8 bh = bfrag(s2, cf);
            #pragma unroll
            for (int rt = 0; rt < 2; ++rt)
                acc2[rt][cf] = __builtin_amdgcn_mfma_f32_16x16x32_bf16(ha[rt], bh, acc2[rt][cf], 0, 0, 0);
        }
    }
    packW(1);                         // W3 (loaded at c=19, long done)

    // ---------------- h2 -> bf16 himg; stage W3; GEMM3 ----------------------
    __syncthreads();                  // GEMM2's wbuf reads done
    storeW();                         // W3 images
    #pragma unroll
    for (int cf = 0; cf < 4; ++cf) {
        float bv = b2[(size_t)ne * H_ + cf * 16 + ccol];
        #pragma unroll
        for (int rt = 0; rt < 2; ++rt)
            #pragma unroll
            for (int reg = 0; reg < 4; ++reg) {
                float hv = fmaxf(acc2[rt][cf][reg] + bv, 0.f);
                himg[(w * 32 + rt * 16 + qrow + reg) * 72 + cf * 16 + ccol] =
                    (short)rtn_bf16(hv);
            }
    }
    __syncthreads();                  // W3 images + h2 visible

    float4v acc3[2][4];
    #pragma unroll
    for (int rt = 0; rt < 2; ++rt)
        #pragma unroll
        for (int cf = 0; cf < 4; ++cf) acc3[rt][cf] = (float4v)0.f;
    #pragma unroll
    for (int s2 = 0; s2 < 2; ++s2) {
        short8 ha[2];
        #pragma unroll
        for (int rt = 0; rt < 2; ++rt)
            ha[rt] = *(const short8*)&himg[(w * 32 + rt * 16 + lrow) * 72 + s2 * 32 + dseg];
        #pragma unroll
        for (int cf = 0; cf < 4; ++cf) {
            short8 bh = bfrag(s2, cf);
            #pragma unroll
            for (int rt = 0; rt < 2; ++rt)
                acc3[rt][cf] = __builtin_amdgcn_mfma_f32_16x16x32_bf16(ha[rt], bh, acc3[rt][cf], 0, 0, 0);
        }
    }

    // ---------------- err epilogue ----------------
    {
        float b3v[4];
        #pragma unroll
        for (int cf = 0; cf < 4; ++cf) b3v[cf] = b3[(size_t)ne * D_ + cf * 16 + ccol];

        #pragma unroll
        for (int rt = 0; rt < 2; ++rt) {
            #pragma unroll
            for (int reg = 0; reg < 4; ++reg) {
                const int m  = rowbase + rt * 16 + qrow + reg;
                const int mc = m < M_ ? m : M_ - 1;
                const int b = mc / TW, t = mc % TW;
                const float* yp = x + ((size_t)(b * T_ + t + 2) * N_ + n) * D_;
                float s = 0.f;
                #pragma unroll
                for (int cf = 0; cf < 4; ++cf) {
                    float d = acc3[rt][cf][reg] + b3v[cf] - yp[cf * 16 + ccol];
                    s += d * d;
                }
                s += __shfl_xor(s, 1);
                s += __shfl_xor(s, 2);
                s += __shfl_xor(s, 4);
                s += __shfl_xor(s, 8);
                if (ccol == 0 && m < M_) {
                    err_ws[((size_t)m * N_ + n) * E_ + e] = s * (1.f / 64.f);
                }
            }
        }
    }
}

// ---------------------------------------------------------------------------
// Exact fp32 fix-up for the 128 err cells feeding expert_idx (all b, all e at
// t=TW-1, n=N-1). 256 threads: j = tid&63 output col, q = tid>>6 K-quarter --
// 4x the load ILP of R10's single-wave version (which was ~50 us latency-bound).
__global__ __launch_bounds__(256) void fix_kernel(
    const float* __restrict__ x, const int* __restrict__ nb,
    const float* __restrict__ W1, const float* __restrict__ b1,
    const float* __restrict__ W2, const float* __restrict__ b2,
    const float* __restrict__ W3, const float* __restrict__ b3,
    float* __restrict__ err_ws)
{
    const int b = blockIdx.x >> 3;
    const int e = blockIdx.x & 7;
    const int n = N_ - 1;             // 21
    const int t = TW - 1;             // 58
    const int ne = n * E_ + e;
    const int j = threadIdx.x & 63;
    const int q = threadIdx.x >> 6;   // 0..3

    __shared__ float fbuf[1280];
    __shared__ float part[4][64];
    __shared__ float h1s[64];
    __shared__ float h2s[64];

    for (int i = threadIdx.x; i < 1280; i += 256) {
        int dt = i >> 8, r = i & 255;
        int k = r >> 6, d = r & 63;
        int nk = nb[n * K_ + k];
        fbuf[i] = x[(((size_t)(b * T_ + t + dt)) * N_ + nk) * D_ + d];
    }
    __syncthreads();

    const float* W1p = W1 + (size_t)ne * 1280 * 64;
    float s = 0.f;
    #pragma unroll 8
    for (int k = q * 320; k < q * 320 + 320; ++k) s += fbuf[k] * W1p[(size_t)k * 64 + j];
    part[q][j] = s;
    __syncthreads();
    if (q == 0)
        h1s[j] = fmaxf(part[0][j] + part[1][j] + part[2][j] + part[3][j]
                       + b1[(size_t)ne * H_ + j], 0.f);
    __syncthreads();

    const float* W2p = W2 + (size_t)ne * 4096;
    s = 0.f;
    #pragma unroll
    for (int k = q * 16; k < q * 16 + 16; ++k) s += h1s[k] * W2p[k * 64 + j];
    part[q][j] = s;
    __syncthreads();
    if (q == 0)
        h2s[j] = fmaxf(part[0][j] + part[1][j] + part[2][j] + part[3][j]
                       + b2[(size_t)ne * H_ + j], 0.f);
    __syncthreads();

    const float* W3p = W3 + (size_t)ne * 4096;
    s = 0.f;
    #pragma unroll
    for (int k = q * 16; k < q * 16 + 16; ++k) s += h2s[k] * W3p[k * 64 + j];
    part[q][j] = s;
    __syncthreads();
    if (q == 0) {
        float pred = part[0][j] + part[1][j] + part[2][j] + part[3][j]
                   + b3[(size_t)ne * D_ + j];
        float y = x[(((size_t)(b * T_ + t + 2)) * N_ + n) * D_ + j];
        float d = pred - y;
        float sq = d * d;
        sq += __shfl_xor(sq, 1);
        sq += __shfl_xor(sq, 2);
        sq += __shfl_xor(sq, 4);
        sq += __shfl_xor(sq, 8);
        sq += __shfl_xor(sq, 16);
        sq += __shfl_xor(sq, 32);
        if (j == 0) {
            int m = b * TW + t;
            err_ws[((size_t)m * N_ + n) * E_ + e] = sq * (1.f / 64.f);
        }
    }
}

// ---------------------------------------------------------------------------
// Reduce: 82 blocks x 256; per-block tree + one atomicAdd (out[0] zeroed by
// xtrunc). Replaces R10's single-block version (~30 us on one CU).
__global__ __launch_bounds__(256) void moe_reduce_kernel(
    const float* __restrict__ err_ws, float* __restrict__ out)
{
    const int tid = threadIdx.x;
    const int idx = blockIdx.x * 256 + tid;
    float v = 0.f;
    if (idx < M_ * N_) {
        const int m = idx / N_, n = idx % N_;
        const float* ep = err_ws + (size_t)idx * E_;
        float ev[E_];
        float4 e0 = *(const float4*)ep;
        float4 e1 = *(const float4*)(ep + 4);
        ev[0] = e0.x; ev[1] = e0.y; ev[2] = e0.z; ev[3] = e0.w;
        ev[4] = e1.x; ev[5] = e1.y; ev[6] = e1.z; ev[7] = e1.w;
        float mn = ev[0];
        int am = 0;
        #pragma unroll
        for (int i = 1; i < E_; ++i) {
            if (ev[i] < mn) { mn = ev[i]; am = i; }
        }
        float p[E_];
        float Z = 0.f;
        #pragma unroll
        for (int i = 0; i < E_; ++i) { p[i] = expf(mn - ev[i]); Z += p[i]; }
        const float invZ = 1.f / Z;
        float kl = 0.f;
        #pragma unroll
        for (int i = 0; i < E_; ++i) {
            float q = p[i] * invZ;
            kl += q * (logf(q + 1e-9f) + 2.0794415416798357f);  // log(8)
        }
        v = mn + 0.01f * kl;
        const int t = m % TW, b = m / TW;
        if (t == TW - 1 && n == N_ - 1) out[1 + b] = (float)am;
    }
    __shared__ float sd[256];
    sd[tid] = v;
    __syncthreads();
    for (int s = 128; s > 0; s >>= 1) {
        if (tid < s) sd[tid] += sd[tid + s];
        __syncthreads();
    }
    if (tid == 0) atomicAdd(out, sd[0] * (1.f / 20160.f));  // / B / (N-1) / (T-4)
}

extern "C" void kernel_launch(void* const* d_in, const int* in_sizes, int n_in,
                              void* d_out, int out_size, void* d_ws, size_t ws_size,
                              hipStream_t stream)
{
    const float* x  = (const float*)d_in[0];
    const int*   nb = (const int*)d_in[1];
    const float* W1 = (const float*)d_in[2];
    const float* b1 = (const float*)d_in[3];
    const float* W2 = (const float*)d_in[4];
    const float* b2 = (const float*)d_in[5];
    const float* W3 = (const float*)d_in[6];
    const float* b3 = (const float*)d_in[7];
    float* out    = (float*)d_out;
    float* err_ws = (float*)d_ws;
    short* xh     = (short*)((char*)d_ws + XH_OFF);

    hipLaunchKernelGGL(xtrunc_kernel, dim3((XTOT / 4 + 255) / 256), dim3(256), 0, stream,
                       x, xh, out);
    hipLaunchKernelGGL(moe_err_kernel, dim3(NE_ * 8), dim3(256), 0, stream,
                       x, xh, nb, W1, W2, W3, b1, b2, b3, err_ws);
    hipLaunchKernelGGL(fix_kernel, dim3(B_ * E_), dim3(256), 0, stream,
                       x, nb, W1, b1, W2, b2, W3, b3, err_ws);
    const int nred = (M_ * N_ + 255) / 256;
    hipLaunchKernelGGL(moe_reduce_kernel, dim3(nred), dim3(256), 0, stream, err_ws, out);
}